// Round 1
// baseline (2602.673 us; speedup 1.0000x reference)
//
#include <hip/hip_runtime.h>
#include <hip/hip_bf16.h>
#include <cstdint>
#include <cstddef>

typedef __attribute__((ext_vector_type(4))) float f32x4;
typedef __attribute__((ext_vector_type(8))) short short8;
typedef unsigned short u16;
typedef __attribute__((ext_vector_type(8))) unsigned short u16x8;
typedef __attribute__((ext_vector_type(4))) unsigned short u16x4;

// ---------- helpers ----------
__device__ __forceinline__ u16 f2bf(float f) {
  union { float f; unsigned u; } v; v.f = f;
  unsigned r = v.u + 0x7FFFu + ((v.u >> 16) & 1u);
  return (u16)(r >> 16);
}
__device__ __forceinline__ float bf2f(u16 h) {
  union { unsigned u; float f; } v; v.u = ((unsigned)h) << 16;
  return v.f;
}
__device__ __forceinline__ void gload16(const u16* g, const u16* l) {
  __builtin_amdgcn_global_load_lds((const __attribute__((address_space(1))) void*)g,
                                   (__attribute__((address_space(3))) void*)l, 16, 0, 0);
}

// ---------- prep: W2t = transpose(concat(Wq,Wk,Wv,tc_W)) duplicated along K (hi|lo), zero-padded to N=3200 ----------
__global__ __launch_bounds__(256) void prep_w2t(
    const float* __restrict__ Wq, const float* __restrict__ Wk, const float* __restrict__ Wv,
    const float* __restrict__ tc, u16* __restrict__ W2t)
{
  __shared__ float t[32][33];
  const int tx = threadIdx.x, ty = threadIdx.y;   // 32 x 8
  const int k0 = blockIdx.x * 32, n0 = blockIdx.y * 32;
  const float* src = nullptr; int col = 0, sw = 0;
  if      (n0 < 1024) { src = Wq; col = n0;        sw = 1024; }
  else if (n0 < 2048) { src = Wk; col = n0 - 1024; sw = 1024; }
  else if (n0 < 3072) { src = Wv; col = n0 - 2048; sw = 1024; }
  else if (n0 < 3104) { src = tc; col = n0 - 3072; sw = 32;   }
  if (src) {
    #pragma unroll
    for (int r = 0; r < 4; r++) {
      int k = k0 + ty + r * 8;
      t[ty + r * 8][tx] = src[(size_t)k * sw + col + tx];
    }
  }
  __syncthreads();
  #pragma unroll
  for (int r = 0; r < 4; r++) {
    int n = n0 + ty + r * 8, k = k0 + tx;
    u16 v = src ? f2bf(t[tx][ty + r * 8]) : (u16)0;
    W2t[(size_t)n * 2048 + k] = v;
    W2t[(size_t)n * 2048 + 1024 + k] = v;
  }
}

// ---------- prep: generic fp32 [R][C] -> bf16 transposed [C][R], batched over z ----------
__global__ __launch_bounds__(256) void transpose_bf(
    const float* __restrict__ src, u16* __restrict__ dst, int R, int C)
{
  __shared__ float t[32][33];
  const int tx = threadIdx.x, ty = threadIdx.y;
  const size_t zoff = (size_t)blockIdx.z * R * C;
  src += zoff; dst += zoff;
  const int c0 = blockIdx.x * 32, r0 = blockIdx.y * 32;
  #pragma unroll
  for (int r = 0; r < 4; r++)
    t[ty + r * 8][tx] = src[(size_t)(r0 + ty + r * 8) * C + c0 + tx];
  __syncthreads();
  #pragma unroll
  for (int r = 0; r < 4; r++)
    dst[(size_t)(c0 + ty + r * 8) * R + r0 + tx] = f2bf(t[tx][ty + r * 8]);
}

// ---------- prep: x fp32 -> A2 bf16 [65536][2048] = [hi | lo] ----------
__global__ __launch_bounds__(256) void split_x(const float* __restrict__ x, u16* __restrict__ A2)
{
  int i = blockIdx.x * 256 + threadIdx.x;      // 16,777,216 float4s
  f32x4 v = ((const f32x4*)x)[i];
  int m = i >> 8, c = (i & 255) * 4;
  u16x4 hi, lo;
  #pragma unroll
  for (int j = 0; j < 4; j++) {
    u16 h = f2bf(v[j]);
    hi[j] = h;
    lo[j] = f2bf(v[j] - bf2f(h));
  }
  *(u16x4*)&A2[(size_t)m * 2048 + c] = hi;
  *(u16x4*)&A2[(size_t)m * 2048 + 1024 + c] = lo;
}

// ---------- core GEMM: C[M,N] = A[M,K] @ Bt[N,K]^T, 128x128 tile, 4 waves, 16x16x32 bf16 MFMA ----------
// MODE 0: QKV+flat scatter  MODE 1: pc (+bias,relu,f32)  MODE 2: hv per-head (+bias,bf16)
// MODE 3: alp (+alp_b+pos_bias, bf16)  MODE 4: final (+bo, f32)
template<int MODE>
__global__ __launch_bounds__(256) void gemm_bt(
    const u16* __restrict__ A, const u16* __restrict__ Bt, int K,
    void* __restrict__ o0, void* __restrict__ o1, void* __restrict__ o2, void* __restrict__ o3,
    const float* __restrict__ bias0, const float* __restrict__ bias1)
{
  __shared__ __align__(16) u16 lA[128 * 32];
  __shared__ __align__(16) u16 lB[128 * 32];
  const int tid = threadIdx.x;
  const int wid = tid >> 6, lane = tid & 63;
  const int wm = wid >> 1, wn = wid & 1;
  const int bn = blockIdx.x, bm = blockIdx.y;
  if (MODE == 2) Bt += (size_t)blockIdx.z * 256 * 256;

  f32x4 acc[4][4];
  #pragma unroll
  for (int i = 0; i < 4; i++)
    #pragma unroll
    for (int j = 0; j < 4; j++)
      #pragma unroll
      for (int r = 0; r < 4; r++) acc[i][j][r] = 0.f;

  const u16* Arow = A + (size_t)(bm * 128) * K;
  const u16* Brow = Bt + (size_t)(bn * 128) * K;

  for (int k0 = 0; k0 < K; k0 += 32) {
    #pragma unroll
    for (int i = 0; i < 2; i++) {
      int c = wid * 128 + i * 64 + lane;          // chunk 0..511 (16B each)
      int row = c >> 2, col = (c & 3) * 8;
      gload16(Arow + (size_t)row * K + k0 + col, &lA[(wid * 128 + i * 64) * 8]);
      gload16(Brow + (size_t)row * K + k0 + col, &lB[(wid * 128 + i * 64) * 8]);
    }
    __syncthreads();
    short8 af[4], bfr[4];
    #pragma unroll
    for (int f = 0; f < 4; f++) {
      af[f]  = *(const short8*)&lA[(wm * 64 + f * 16 + (lane & 15)) * 32 + (lane >> 4) * 8];
      bfr[f] = *(const short8*)&lB[(wn * 64 + f * 16 + (lane & 15)) * 32 + (lane >> 4) * 8];
    }
    #pragma unroll
    for (int fm = 0; fm < 4; fm++)
      #pragma unroll
      for (int fn = 0; fn < 4; fn++)
        acc[fm][fn] = __builtin_amdgcn_mfma_f32_16x16x32_bf16(af[fm], bfr[fn], acc[fm][fn], 0, 0, 0);
    __syncthreads();
  }

  const int lr = lane >> 4, lc = lane & 15;
  #pragma unroll
  for (int fm = 0; fm < 4; fm++) {
    #pragma unroll
    for (int fn = 0; fn < 4; fn++) {
      #pragma unroll
      for (int r = 0; r < 4; r++) {
        int gm = bm * 128 + wm * 64 + fm * 16 + lr * 4 + r;
        int gn = bn * 128 + wn * 64 + fn * 16 + lc;
        float val = acc[fm][fn][r];
        if (MODE == 0) {
          int b = gm >> 6, s = gm & 63;
          if (gn < 3072) {
            int which = gn >> 10, hh = (gn >> 5) & 31, d = gn & 31;
            u16* dst = (which == 0) ? (u16*)o0 : (which == 1) ? (u16*)o1 : (u16*)o2;
            dst[(((size_t)b * 32 + hh) * 64 + s) * 32 + d] = f2bf(val);
          } else if (gn < 3104) {
            ((u16*)o3)[(size_t)b * 2048 + s * 32 + (gn - 3072)] = f2bf(val);
          }
        } else if (MODE == 1) {
          float v = val + bias0[gn];
          ((float*)o0)[(size_t)gm * 256 + gn] = v > 0.f ? v : 0.f;
        } else if (MODE == 2) {
          int h = blockIdx.z;
          ((u16*)o0)[((size_t)gm * 32 + h) * 256 + gn] = f2bf(val + bias0[h * 256 + gn]);
        } else if (MODE == 3) {
          ((u16*)o0)[(size_t)gm * 4096 + gn] = f2bf(val + bias0[gn] + bias1[(gm & 31) * 4096 + gn]);
        } else {
          ((float*)o0)[(size_t)gm * 1024 + gn] = val + bias0[gn];
        }
      }
    }
  }
}

// ---------- LayerNorm over 256 cols ----------
__global__ __launch_bounds__(256) void ln_kernel(
    const float* __restrict__ pv, const float* __restrict__ g, const float* __restrict__ b2,
    u16* __restrict__ out)
{
  __shared__ float red[256];
  const int bi = blockIdx.x, t = threadIdx.x;
  float v = pv[(size_t)bi * 256 + t];
  red[t] = v; __syncthreads();
  #pragma unroll
  for (int o = 128; o > 0; o >>= 1) { if (t < o) red[t] += red[t + o]; __syncthreads(); }
  float mu = red[0] * (1.f / 256.f);
  __syncthreads();
  float dv = v - mu;
  red[t] = dv * dv; __syncthreads();
  #pragma unroll
  for (int o = 128; o > 0; o >>= 1) { if (t < o) red[t] += red[t + o]; __syncthreads(); }
  float var = red[0] * (1.f / 256.f);
  float rs = rsqrtf(var + 1e-5f);
  out[(size_t)bi * 256 + t] = f2bf(dv * rs * g[t] + b2[t]);
}

// ---------- attention core: one wave per (b,h); fp32 scores/softmax/PV ----------
__global__ __launch_bounds__(64) void attn_kernel(
    const u16* __restrict__ qb, const u16* __restrict__ kb, const u16* __restrict__ vb,
    const u16* __restrict__ lg, u16* __restrict__ aout)
{
  __shared__ __align__(16) float kf[64 * 32];
  __shared__ __align__(16) float vf[64 * 32];
  const int bid = blockIdx.x;          // b*32 + h
  const int lane = threadIdx.x;
  const size_t base = (size_t)bid * 2048;

  #pragma unroll
  for (int i = 0; i < 4; i++) {
    int chunk = i * 64 + lane;
    u16x8 u = *(const u16x8*)(kb + base + chunk * 8);
    u16x8 w = *(const u16x8*)(vb + base + chunk * 8);
    #pragma unroll
    for (int j = 0; j < 8; j++) { kf[chunk * 8 + j] = bf2f(u[j]); vf[chunk * 8 + j] = bf2f(w[j]); }
  }
  float qr[32];
  const u16* qrow = qb + base + lane * 32;
  #pragma unroll
  for (int c = 0; c < 4; c++) {
    u16x8 u = *(const u16x8*)(qrow + c * 8);
    #pragma unroll
    for (int j = 0; j < 8; j++) qr[c * 8 + j] = bf2f(u[j]);
  }
  __syncthreads();

  const float scale = 0.17677669529663687f;   // 1/sqrt(32)
  float s[64];
  const u16* lgrow = lg + (size_t)bid * 4096 + lane * 64;
  #pragma unroll
  for (int c = 0; c < 8; c++) {
    u16x8 u = *(const u16x8*)(lgrow + c * 8);
    #pragma unroll
    for (int jj = 0; jj < 8; jj++) {
      int j = c * 8 + jj;
      float a0 = 0.f;
      const f32x4* kr = (const f32x4*)&kf[j * 32];
      #pragma unroll
      for (int d4 = 0; d4 < 8; d4++) {
        f32x4 kk = kr[d4];
        a0 += qr[d4*4+0]*kk[0] + qr[d4*4+1]*kk[1] + qr[d4*4+2]*kk[2] + qr[d4*4+3]*kk[3];
      }
      s[j] = a0 * scale + bf2f(u[jj]);
    }
  }
  float m = s[0];
  #pragma unroll
  for (int j = 1; j < 64; j++) m = fmaxf(m, s[j]);
  float sum = 0.f;
  #pragma unroll
  for (int j = 0; j < 64; j++) { s[j] = __expf(s[j] - m); sum += s[j]; }
  float inv = 1.f / sum;

  float o[32];
  #pragma unroll
  for (int d = 0; d < 32; d++) o[d] = 0.f;
  #pragma unroll
  for (int j = 0; j < 64; j++) {
    float pj = s[j];
    const f32x4* vr = (const f32x4*)&vf[j * 32];
    #pragma unroll
    for (int d4 = 0; d4 < 8; d4++) {
      f32x4 vv = vr[d4];
      o[d4*4+0] += pj*vv[0]; o[d4*4+1] += pj*vv[1]; o[d4*4+2] += pj*vv[2]; o[d4*4+3] += pj*vv[3];
    }
  }
  const int b = bid >> 5, h = bid & 31;
  u16* dst = aout + ((size_t)(b * 64 + lane)) * 1024 + h * 32;
  #pragma unroll
  for (int c = 0; c < 4; c++) {
    u16x8 u;
    #pragma unroll
    for (int j = 0; j < 8; j++) u[j] = f2bf(o[c * 8 + j] * inv);
    *(u16x8*)(dst + c * 8) = u;
  }
}

// ---------- launch ----------
extern "C" void kernel_launch(void* const* d_in, const int* in_sizes, int n_in,
                              void* d_out, int out_size, void* d_ws, size_t ws_size,
                              hipStream_t stream) {
  const float* x       = (const float*)d_in[0];
  const float* Wq      = (const float*)d_in[1];
  const float* Wk      = (const float*)d_in[2];
  const float* Wv      = (const float*)d_in[3];
  const float* Wo      = (const float*)d_in[4];
  const float* bo      = (const float*)d_in[5];
  const float* pos_b   = (const float*)d_in[6];
  const float* tc_W    = (const float*)d_in[7];
  const float* pc_W    = (const float*)d_in[8];
  const float* pc_b    = (const float*)d_in[9];
  const float* ln_g    = (const float*)d_in[10];
  const float* ln_b    = (const float*)d_in[11];
  const float* hp_W    = (const float*)d_in[12];
  const float* hp_b    = (const float*)d_in[13];
  const float* alp_W   = (const float*)d_in[14];
  const float* alp_b   = (const float*)d_in[15];
  float* out = (float*)d_out;

  char* w = (char*)d_ws;
  u16* A2     = (u16*)w;              // 268,435,456 B — aliased with logits (A2 dead after gemm<0>)
  u16* logits = A2;                   w += 268435456;
  u16* qb     = (u16*)w;              w += 134217728;
  u16* kb     = (u16*)w;              w += 134217728;
  u16* vb     = (u16*)w;              w += 134217728;
  u16* aout   = (u16*)w;              w += 134217728;
  u16* W2t    = (u16*)w;              w += (size_t)3200 * 2048 * 2;
  u16* pcWt   = (u16*)w;              w += (size_t)256 * 2048 * 2;
  u16* hpWt   = (u16*)w;              w += (size_t)32 * 256 * 256 * 2;
  u16* alpWt  = (u16*)w;              w += (size_t)4096 * 256 * 2;
  u16* WoT    = (u16*)w;              w += (size_t)1024 * 1024 * 2;
  u16* flatb  = (u16*)w;              w += (size_t)1024 * 2048 * 2;
  float* pvtmp= (float*)w;            w += (size_t)1024 * 256 * 4;
  u16* pvb    = (u16*)w;              w += (size_t)1024 * 256 * 2;
  u16* hvb    = (u16*)w;              w += (size_t)32768 * 256 * 2;

  prep_w2t    <<<dim3(32, 100),    dim3(32, 8), 0, stream>>>(Wq, Wk, Wv, tc_W, W2t);
  transpose_bf<<<dim3(8, 64, 1),   dim3(32, 8), 0, stream>>>(pc_W, pcWt, 2048, 256);
  transpose_bf<<<dim3(8, 8, 32),   dim3(32, 8), 0, stream>>>(hp_W, hpWt, 256, 256);
  transpose_bf<<<dim3(128, 8, 1),  dim3(32, 8), 0, stream>>>(alp_W, alpWt, 256, 4096);
  transpose_bf<<<dim3(32, 32, 1),  dim3(32, 8), 0, stream>>>(Wo, WoT, 1024, 1024);
  split_x     <<<65536, 256, 0, stream>>>(x, A2);

  gemm_bt<0><<<dim3(25, 512),    256, 0, stream>>>(A2, W2t, 2048, qb, kb, vb, flatb, nullptr, nullptr);
  gemm_bt<1><<<dim3(2, 8),       256, 0, stream>>>(flatb, pcWt, 2048, pvtmp, nullptr, nullptr, nullptr, pc_b, nullptr);
  ln_kernel <<<1024, 256, 0, stream>>>(pvtmp, ln_g, ln_b, pvb);
  gemm_bt<2><<<dim3(2, 8, 32),   256, 0, stream>>>(pvb, hpWt, 256, hvb, nullptr, nullptr, nullptr, hp_b, nullptr);
  gemm_bt<3><<<dim3(32, 256),    256, 0, stream>>>(hvb, alpWt, 256, logits, nullptr, nullptr, nullptr, alp_b, pos_b);
  attn_kernel<<<32768, 64, 0, stream>>>(qb, kb, vb, logits, aout);
  gemm_bt<4><<<dim3(8, 512),     256, 0, stream>>>(aout, WoT, 1024, out, nullptr, nullptr, nullptr, bo, nullptr);
}

// Round 2
// 1393.160 us; speedup vs baseline: 1.8682x; 1.8682x over previous
//
#include <hip/hip_runtime.h>
#include <hip/hip_bf16.h>
#include <cstdint>
#include <cstddef>

typedef __attribute__((ext_vector_type(4))) float f32x4;
typedef __attribute__((ext_vector_type(8))) short short8;
typedef unsigned short u16;
typedef __attribute__((ext_vector_type(8))) unsigned short u16x8;
typedef __attribute__((ext_vector_type(4))) unsigned short u16x4;

// ---------- helpers ----------
__device__ __forceinline__ u16 f2bf(float f) {
  union { float f; unsigned u; } v; v.f = f;
  unsigned r = v.u + 0x7FFFu + ((v.u >> 16) & 1u);
  return (u16)(r >> 16);
}
__device__ __forceinline__ float bf2f(u16 h) {
  union { unsigned u; float f; } v; v.u = ((unsigned)h) << 16;
  return v.f;
}
__device__ __forceinline__ void gload16(const u16* g, const u16* l) {
  __builtin_amdgcn_global_load_lds((const __attribute__((address_space(1))) void*)g,
                                   (__attribute__((address_space(3))) void*)l, 16, 0, 0);
}

// ---------- prep: W2t = transpose(concat(Wq,Wk,Wv,tc_W)) as bf16 [3200][1024], zero-padded rows 3104..3199 ----------
__global__ __launch_bounds__(256) void prep_w2t(
    const float* __restrict__ Wq, const float* __restrict__ Wk, const float* __restrict__ Wv,
    const float* __restrict__ tc, u16* __restrict__ W2t)
{
  __shared__ float t[32][33];
  const int tx = threadIdx.x, ty = threadIdx.y;   // 32 x 8
  const int k0 = blockIdx.x * 32, n0 = blockIdx.y * 32;
  const float* src = nullptr; int col = 0, sw = 0;
  if      (n0 < 1024) { src = Wq; col = n0;        sw = 1024; }
  else if (n0 < 2048) { src = Wk; col = n0 - 1024; sw = 1024; }
  else if (n0 < 3072) { src = Wv; col = n0 - 2048; sw = 1024; }
  else if (n0 < 3104) { src = tc; col = n0 - 3072; sw = 32;   }
  if (src) {
    #pragma unroll
    for (int r = 0; r < 4; r++) {
      int k = k0 + ty + r * 8;
      t[ty + r * 8][tx] = src[(size_t)k * sw + col + tx];
    }
  }
  __syncthreads();
  #pragma unroll
  for (int r = 0; r < 4; r++) {
    int n = n0 + ty + r * 8, k = k0 + tx;
    u16 v = src ? f2bf(t[tx][ty + r * 8]) : (u16)0;
    W2t[(size_t)n * 1024 + k] = v;
  }
}

// ---------- prep: generic fp32 [R][C] -> bf16 transposed [C][R], batched over z ----------
__global__ __launch_bounds__(256) void transpose_bf(
    const float* __restrict__ src, u16* __restrict__ dst, int R, int C)
{
  __shared__ float t[32][33];
  const int tx = threadIdx.x, ty = threadIdx.y;
  const size_t zoff = (size_t)blockIdx.z * R * C;
  src += zoff; dst += zoff;
  const int c0 = blockIdx.x * 32, r0 = blockIdx.y * 32;
  #pragma unroll
  for (int r = 0; r < 4; r++)
    t[ty + r * 8][tx] = src[(size_t)(r0 + ty + r * 8) * C + c0 + tx];
  __syncthreads();
  #pragma unroll
  for (int r = 0; r < 4; r++)
    dst[(size_t)(c0 + ty + r * 8) * R + r0 + tx] = f2bf(t[tx][ty + r * 8]);
}

// ---------- prep: x fp32 -> bf16 (linear) ----------
__global__ __launch_bounds__(256) void cvt_x(const float* __restrict__ x, u16* __restrict__ A2)
{
  size_t i = (size_t)blockIdx.x * 256 + threadIdx.x;   // 16,777,216 float4 groups
  f32x4 v = ((const f32x4*)x)[i];
  u16x4 o;
  #pragma unroll
  for (int j = 0; j < 4; j++) o[j] = f2bf(v[j]);
  ((u16x4*)A2)[i] = o;
}

// ---------- core GEMM: C[M,N] = A[M,K] @ Bt[N,K]^T, 128x128 tile, 4 waves, 16x16x32 bf16 MFMA ----------
// MODE 0: QKV+flat scatter  MODE 1: pc (+bias,relu,f32)  MODE 2: hv per-head (+bias,bf16)
// MODE 3: alp (+alp_b+pos_bias, bf16)  MODE 4: final (+bo, f32)
template<int MODE>
__global__ __launch_bounds__(256) void gemm_bt(
    const u16* __restrict__ A, const u16* __restrict__ Bt, int K,
    void* __restrict__ o0, void* __restrict__ o1, void* __restrict__ o2, void* __restrict__ o3,
    const float* __restrict__ bias0, const float* __restrict__ bias1)
{
  __shared__ __align__(16) u16 lA[128 * 32];
  __shared__ __align__(16) u16 lB[128 * 32];
  const int tid = threadIdx.x;
  const int wid = tid >> 6, lane = tid & 63;
  const int wm = wid >> 1, wn = wid & 1;
  const int bn = blockIdx.x, bm = blockIdx.y;
  if (MODE == 2) Bt += (size_t)blockIdx.z * 256 * 256;

  f32x4 acc[4][4];
  #pragma unroll
  for (int i = 0; i < 4; i++)
    #pragma unroll
    for (int j = 0; j < 4; j++)
      #pragma unroll
      for (int r = 0; r < 4; r++) acc[i][j][r] = 0.f;

  const u16* Arow = A + (size_t)(bm * 128) * K;
  const u16* Brow = Bt + (size_t)(bn * 128) * K;

  for (int k0 = 0; k0 < K; k0 += 32) {
    #pragma unroll
    for (int i = 0; i < 2; i++) {
      int c = wid * 128 + i * 64 + lane;          // chunk 0..511 (16B each)
      int row = c >> 2, col = (c & 3) * 8;
      gload16(Arow + (size_t)row * K + k0 + col, &lA[(wid * 128 + i * 64) * 8]);
      gload16(Brow + (size_t)row * K + k0 + col, &lB[(wid * 128 + i * 64) * 8]);
    }
    __syncthreads();
    short8 af[4], bfr[4];
    #pragma unroll
    for (int f = 0; f < 4; f++) {
      af[f]  = *(const short8*)&lA[(wm * 64 + f * 16 + (lane & 15)) * 32 + (lane >> 4) * 8];
      bfr[f] = *(const short8*)&lB[(wn * 64 + f * 16 + (lane & 15)) * 32 + (lane >> 4) * 8];
    }
    #pragma unroll
    for (int fm = 0; fm < 4; fm++)
      #pragma unroll
      for (int fn = 0; fn < 4; fn++)
        acc[fm][fn] = __builtin_amdgcn_mfma_f32_16x16x32_bf16(af[fm], bfr[fn], acc[fm][fn], 0, 0, 0);
    __syncthreads();
  }

  const int lr = lane >> 4, lc = lane & 15;
  #pragma unroll
  for (int fm = 0; fm < 4; fm++) {
    #pragma unroll
    for (int fn = 0; fn < 4; fn++) {
      #pragma unroll
      for (int r = 0; r < 4; r++) {
        int gm = bm * 128 + wm * 64 + fm * 16 + lr * 4 + r;
        int gn = bn * 128 + wn * 64 + fn * 16 + lc;
        float val = acc[fm][fn][r];
        if (MODE == 0) {
          int b = gm >> 6, s = gm & 63;
          if (gn < 3072) {
            int which = gn >> 10, hh = (gn >> 5) & 31, d = gn & 31;
            u16* dst = (which == 0) ? (u16*)o0 : (which == 1) ? (u16*)o1 : (u16*)o2;
            dst[(((size_t)b * 32 + hh) * 64 + s) * 32 + d] = f2bf(val);
          } else if (gn < 3104) {
            ((u16*)o3)[(size_t)b * 2048 + s * 32 + (gn - 3072)] = f2bf(val);
          }
        } else if (MODE == 1) {
          float v = val + bias0[gn];
          ((float*)o0)[(size_t)gm * 256 + gn] = v > 0.f ? v : 0.f;
        } else if (MODE == 2) {
          int h = blockIdx.z;
          ((u16*)o0)[((size_t)gm * 32 + h) * 256 + gn] = f2bf(val + bias0[h * 256 + gn]);
        } else if (MODE == 3) {
          ((u16*)o0)[(size_t)gm * 4096 + gn] = f2bf(val + bias0[gn] + bias1[(gm & 31) * 4096 + gn]);
        } else {
          ((float*)o0)[(size_t)gm * 1024 + gn] = val + bias0[gn];
        }
      }
    }
  }
}

// ---------- LayerNorm over 256 cols ----------
__global__ __launch_bounds__(256) void ln_kernel(
    const float* __restrict__ pv, const float* __restrict__ g, const float* __restrict__ b2,
    u16* __restrict__ out)
{
  __shared__ float red[256];
  const int bi = blockIdx.x, t = threadIdx.x;
  float v = pv[(size_t)bi * 256 + t];
  red[t] = v; __syncthreads();
  #pragma unroll
  for (int o = 128; o > 0; o >>= 1) { if (t < o) red[t] += red[t + o]; __syncthreads(); }
  float mu = red[0] * (1.f / 256.f);
  __syncthreads();
  float dv = v - mu;
  red[t] = dv * dv; __syncthreads();
  #pragma unroll
  for (int o = 128; o > 0; o >>= 1) { if (t < o) red[t] += red[t + o]; __syncthreads(); }
  float var = red[0] * (1.f / 256.f);
  float rs = rsqrtf(var + 1e-5f);
  out[(size_t)bi * 256 + t] = f2bf(dv * rs * g[t] + b2[t]);
}

// ---------- attention core, MFMA version: one wave per (b,h) ----------
// S^T[j][q] = mfma(A=K rows, B=Q rows);  O[q][d] via O^T = mfma(A=V^T, B=P rows)
__global__ __launch_bounds__(64) void attn_mfma(
    const u16* __restrict__ qb, const u16* __restrict__ kb, const u16* __restrict__ vb,
    const u16* __restrict__ lg, u16* __restrict__ aout)
{
  __shared__ __align__(16) u16 vT[32 * 64];   // [d][j], XOR-swizzled within row
  __shared__ __align__(16) u16 Pl[64 * 64];   // [q][j], XOR-swizzled within row
  const int bid = blockIdx.x;                 // b*32 + h
  const int lane = threadIdx.x;
  const int g = lane >> 4, l15 = lane & 15;
  const size_t base = (size_t)bid * 2048;

  // --- stage V transposed into LDS: lane = source row j ---
  {
    const u16* vrow = vb + base + lane * 32;
    u16x8 vv[4];
    #pragma unroll
    for (int c = 0; c < 4; c++) vv[c] = *(const u16x8*)(vrow + c * 8);
    #pragma unroll
    for (int d = 0; d < 32; d++)
      vT[d * 64 + (lane ^ ((d & 7) << 3))] = vv[d >> 3][d & 7];
  }

  // --- Q,K fragments straight from global (coalesced 1KB per load inst) ---
  short8 qf[4], kf[4];
  #pragma unroll
  for (int t = 0; t < 4; t++) {
    qf[t] = *(const short8*)(qb + base + (size_t)(t * 16 + l15) * 32 + g * 8);
    kf[t] = *(const short8*)(kb + base + (size_t)(t * 16 + l15) * 32 + g * 8);
  }

  // --- scores S^T[j][q]: j = tm*16 + g*4 + r, q = tn*16 + l15 ---
  f32x4 s[4][4];
  #pragma unroll
  for (int tm = 0; tm < 4; tm++)
    #pragma unroll
    for (int tn = 0; tn < 4; tn++)
      #pragma unroll
      for (int r = 0; r < 4; r++) s[tm][tn][r] = 0.f;
  #pragma unroll
  for (int tm = 0; tm < 4; tm++)
    #pragma unroll
    for (int tn = 0; tn < 4; tn++)
      s[tm][tn] = __builtin_amdgcn_mfma_f32_16x16x32_bf16(kf[tm], qf[tn], s[tm][tn], 0, 0, 0);

  // --- add scale + logits, softmax over j per q, write P (unnormalized) to LDS ---
  const float scale = 0.17677669529663687f;   // 1/sqrt(32)
  float inv4[4];
  const u16* lbase = lg + (size_t)bid * 4096;
  #pragma unroll
  for (int tn = 0; tn < 4; tn++) {
    const int q = tn * 16 + l15;
    float mx = -1e30f;
    #pragma unroll
    for (int tm = 0; tm < 4; tm++) {
      u16x4 u = *(const u16x4*)(lbase + (size_t)q * 64 + tm * 16 + g * 4);
      #pragma unroll
      for (int r = 0; r < 4; r++) {
        s[tm][tn][r] = s[tm][tn][r] * scale + bf2f(u[r]);
        mx = fmaxf(mx, s[tm][tn][r]);
      }
    }
    mx = fmaxf(mx, __shfl_xor(mx, 16));
    mx = fmaxf(mx, __shfl_xor(mx, 32));
    float sm = 0.f;
    #pragma unroll
    for (int tm = 0; tm < 4; tm++)
      #pragma unroll
      for (int r = 0; r < 4; r++) {
        float e = __expf(s[tm][tn][r] - mx);
        s[tm][tn][r] = e;
        sm += e;
      }
    sm += __shfl_xor(sm, 16);
    sm += __shfl_xor(sm, 32);
    inv4[tn] = 1.f / sm;
    #pragma unroll
    for (int tm = 0; tm < 4; tm++) {
      u16x4 p;
      #pragma unroll
      for (int r = 0; r < 4; r++) p[r] = f2bf(s[tm][tn][r]);
      *(u16x4*)&Pl[q * 64 + ((tm * 16 + g * 4) ^ ((q & 7) << 3))] = p;
    }
  }
  __syncthreads();

  // --- PV: O^T[d][q] = sum_j V^T[d][j] * P[q][j] ---
  f32x4 o[2][4];
  #pragma unroll
  for (int md = 0; md < 2; md++)
    #pragma unroll
    for (int tn = 0; tn < 4; tn++)
      #pragma unroll
      for (int r = 0; r < 4; r++) o[md][tn][r] = 0.f;
  #pragma unroll
  for (int ks = 0; ks < 2; ks++) {
    short8 vf2[2], pf[4];
    #pragma unroll
    for (int md = 0; md < 2; md++)
      vf2[md] = *(const short8*)&vT[(md * 16 + l15) * 64 + ((ks * 32 + g * 8) ^ ((l15 & 7) << 3))];
    #pragma unroll
    for (int tn = 0; tn < 4; tn++)
      pf[tn] = *(const short8*)&Pl[(tn * 16 + l15) * 64 + ((ks * 32 + g * 8) ^ ((l15 & 7) << 3))];
    #pragma unroll
    for (int md = 0; md < 2; md++)
      #pragma unroll
      for (int tn = 0; tn < 4; tn++)
        o[md][tn] = __builtin_amdgcn_mfma_f32_16x16x32_bf16(vf2[md], pf[tn], o[md][tn], 0, 0, 0);
  }

  // --- write O: aout[(b*64+q)*1024 + h*32 + d], normalize by inv4[tn] ---
  const int b = bid >> 5, h = bid & 31;
  #pragma unroll
  for (int md = 0; md < 2; md++) {
    #pragma unroll
    for (int tn = 0; tn < 4; tn++) {
      const int q = tn * 16 + l15, d0 = md * 16 + g * 4;
      u16x4 u;
      #pragma unroll
      for (int r = 0; r < 4; r++) u[r] = f2bf(o[md][tn][r] * inv4[tn]);
      *(u16x4*)(aout + ((size_t)(b * 64 + q)) * 1024 + h * 32 + d0) = u;
    }
  }
}

// ---------- launch ----------
extern "C" void kernel_launch(void* const* d_in, const int* in_sizes, int n_in,
                              void* d_out, int out_size, void* d_ws, size_t ws_size,
                              hipStream_t stream) {
  const float* x       = (const float*)d_in[0];
  const float* Wq      = (const float*)d_in[1];
  const float* Wk      = (const float*)d_in[2];
  const float* Wv      = (const float*)d_in[3];
  const float* Wo      = (const float*)d_in[4];
  const float* bo      = (const float*)d_in[5];
  const float* pos_b   = (const float*)d_in[6];
  const float* tc_W    = (const float*)d_in[7];
  const float* pc_W    = (const float*)d_in[8];
  const float* pc_b    = (const float*)d_in[9];
  const float* ln_g    = (const float*)d_in[10];
  const float* ln_b    = (const float*)d_in[11];
  const float* hp_W    = (const float*)d_in[12];
  const float* hp_b    = (const float*)d_in[13];
  const float* alp_W   = (const float*)d_in[14];
  const float* alp_b   = (const float*)d_in[15];
  float* out = (float*)d_out;

  char* w = (char*)d_ws;
  u16* A2     = (u16*)w;              // 134 MB bf16 x, dead after gemm<0>
  u16* logits = (u16*)w;              w += 268435456;   // logits aliases A2 region (268 MB)
  u16* qb     = (u16*)w;              w += 134217728;
  u16* kb     = (u16*)w;              w += 134217728;
  u16* vb     = (u16*)w;              w += 134217728;
  u16* aout   = (u16*)w;              w += 134217728;
  u16* W2t    = (u16*)w;              w += (size_t)3200 * 1024 * 2;
  u16* pcWt   = (u16*)w;              w += (size_t)256 * 2048 * 2;
  u16* hpWt   = (u16*)w;              w += (size_t)32 * 256 * 256 * 2;
  u16* alpWt  = (u16*)w;              w += (size_t)4096 * 256 * 2;
  u16* WoT    = (u16*)w;              w += (size_t)1024 * 1024 * 2;
  u16* flatb  = (u16*)w;              w += (size_t)1024 * 2048 * 2;
  float* pvtmp= (float*)w;            w += (size_t)1024 * 256 * 4;
  u16* pvb    = (u16*)w;              w += (size_t)1024 * 256 * 2;
  u16* hvb    = (u16*)w;              w += (size_t)32768 * 256 * 2;

  prep_w2t    <<<dim3(32, 100),    dim3(32, 8), 0, stream>>>(Wq, Wk, Wv, tc_W, W2t);
  transpose_bf<<<dim3(8, 64, 1),   dim3(32, 8), 0, stream>>>(pc_W, pcWt, 2048, 256);
  transpose_bf<<<dim3(8, 8, 32),   dim3(32, 8), 0, stream>>>(hp_W, hpWt, 256, 256);
  transpose_bf<<<dim3(128, 8, 1),  dim3(32, 8), 0, stream>>>(alp_W, alpWt, 256, 4096);
  transpose_bf<<<dim3(32, 32, 1),  dim3(32, 8), 0, stream>>>(Wo, WoT, 1024, 1024);
  cvt_x       <<<65536, 256, 0, stream>>>(x, A2);

  gemm_bt<0><<<dim3(25, 512),    256, 0, stream>>>(A2, W2t, 1024, qb, kb, vb, flatb, nullptr, nullptr);
  gemm_bt<1><<<dim3(2, 8),       256, 0, stream>>>(flatb, pcWt, 2048, pvtmp, nullptr, nullptr, nullptr, pc_b, nullptr);
  ln_kernel <<<1024, 256, 0, stream>>>(pvtmp, ln_g, ln_b, pvb);
  gemm_bt<2><<<dim3(2, 8, 32),   256, 0, stream>>>(pvb, hpWt, 256, hvb, nullptr, nullptr, nullptr, hp_b, nullptr);
  gemm_bt<3><<<dim3(32, 256),    256, 0, stream>>>(hvb, alpWt, 256, logits, nullptr, nullptr, nullptr, alp_b, pos_b);
  attn_mfma <<<32768, 64, 0, stream>>>(qb, kb, vb, logits, aout);
  gemm_bt<4><<<dim3(8, 512),     256, 0, stream>>>(aout, WoT, 1024, out, nullptr, nullptr, nullptr, bo, nullptr);
}